// Round 1
// baseline (827.269 us; speedup 1.0000x reference)
//
#include <hip/hip_runtime.h>
#include <stdint.h>

#define NN 100000
#define NE 3200000

typedef unsigned int uint;
typedef unsigned short ushort;
typedef __attribute__((ext_vector_type(8))) short bf16x8;
typedef __attribute__((ext_vector_type(4))) float f32x4;

static __device__ __forceinline__ float bflo(uint v) {
    uint u = v << 16; return __builtin_bit_cast(float, u);
}
static __device__ __forceinline__ float bfhi(uint v) {
    uint u = v & 0xffff0000u; return __builtin_bit_cast(float, u);
}
static __device__ __forceinline__ float b2f(ushort v) {
    uint u = ((uint)v) << 16; return __builtin_bit_cast(float, u);
}
static __device__ __forceinline__ ushort f2b(float f) {  // RNE fp32->bf16
    uint u = __builtin_bit_cast(uint, f);
    u += 0x7fffu + ((u >> 16) & 1u);
    return (ushort)(u >> 16);
}

// ---------------- CSR build ----------------

__global__ void hist_k(const int* __restrict__ ei, int* __restrict__ ptr) {
    int i = blockIdx.x * blockDim.x + threadIdx.x;
    int stride = gridDim.x * blockDim.x;
    for (; i < NE; i += stride)
        atomicAdd(&ptr[1 + ei[NE + i]], 1);
}

// 2-level inclusive scan over n=NN+1 ints. Block handles 4096 (256 thr x 16).
__global__ __launch_bounds__(256) void scan1_k(int* __restrict__ data, int* __restrict__ part, int n) {
    __shared__ int sd[256];
    int tid = threadIdx.x;
    int base = blockIdx.x * 4096 + tid * 16;
    int v[16];
    int s = 0;
#pragma unroll
    for (int j = 0; j < 16; j++) {
        int i = base + j;
        int t = (i < n) ? data[i] : 0;
        s += t;
        v[j] = s;   // running inclusive within thread
    }
    sd[tid] = s;
    __syncthreads();
    for (int off = 1; off < 256; off <<= 1) {
        int t = (tid >= off) ? sd[tid - off] : 0;
        __syncthreads();
        sd[tid] += t;
        __syncthreads();
    }
    int excl = sd[tid] - s;
#pragma unroll
    for (int j = 0; j < 16; j++) {
        int i = base + j;
        if (i < n) data[i] = v[j] + excl;
    }
    if (tid == 255) part[blockIdx.x] = sd[255];
}

__global__ void scan2_k(int* __restrict__ part, int nb) {
    if (threadIdx.x == 0 && blockIdx.x == 0) {
        int a = 0;
        for (int i = 0; i < nb; i++) { int t = part[i]; part[i] = a; a += t; }
    }
}

__global__ void scan3_k(int* __restrict__ data, const int* __restrict__ part,
                        int* __restrict__ cur, int n) {
    int i = blockIdx.x * blockDim.x + threadIdx.x;
    if (i < n) {
        int v = data[i] + part[i >> 12];
        data[i] = v;
        if (i < NN) cur[i] = v;   // cursor for fill = row start
    }
}

__global__ void fill_k(const int* __restrict__ ei, int* __restrict__ cur, int* __restrict__ col) {
    int i = blockIdx.x * blockDim.x + threadIdx.x;
    int stride = gridDim.x * blockDim.x;
    for (; i < NE; i += stride) {
        int s = ei[i];
        int d = ei[NE + i];
        int pos = atomicAdd(&cur[d], 1);
        col[pos] = s;
    }
}

// ---------------- GEMM1: y1 = bf16( x @ W1^T ), x fp32 [NN,128], W1 [128,128] ----------------
// block = 256 thr (4 waves), block tile 128 rows x 128 cols; wave = 32 rows.

__global__ __launch_bounds__(256) void gemm1_k(const float* __restrict__ x,
                                               const float* __restrict__ W1,
                                               ushort* __restrict__ y1) {
    __shared__ ushort wl[128 * 136];
    int tid = threadIdx.x;
    for (int i = tid; i < 128 * 128; i += 256)
        wl[(i >> 7) * 136 + (i & 127)] = f2b(W1[i]);
    __syncthreads();

    int wave = tid >> 6, lane = tid & 63;
    int lr = lane & 15, lk = (lane >> 4) * 8;
    long rowbase = (long)blockIdx.x * 128 + wave * 32;

    f32x4 acc[2][8] = {};
    for (int kc = 0; kc < 128; kc += 32) {
        bf16x8 a[2];
#pragma unroll
        for (int m = 0; m < 2; m++) {
            long row = rowbase + m * 16 + lr;
            if (row > NN - 1) row = NN - 1;
            const float* p = x + row * 128 + kc + lk;
            float f[8];
            *(float4*)(f)     = *(const float4*)(p);
            *(float4*)(f + 4) = *(const float4*)(p + 4);
            bf16x8 t;
#pragma unroll
            for (int j = 0; j < 8; j++) t[j] = (short)f2b(f[j]);
            a[m] = t;
        }
#pragma unroll
        for (int nb = 0; nb < 8; nb++) {
            bf16x8 b = *(const bf16x8*)&wl[(nb * 16 + lr) * 136 + kc + lk];
            acc[0][nb] = __builtin_amdgcn_mfma_f32_16x16x32_bf16(a[0], b, acc[0][nb], 0, 0, 0);
            acc[1][nb] = __builtin_amdgcn_mfma_f32_16x16x32_bf16(a[1], b, acc[1][nb], 0, 0, 0);
        }
    }
    int rq = (lane >> 4) * 4;
#pragma unroll
    for (int m = 0; m < 2; m++) {
#pragma unroll
        for (int r = 0; r < 4; r++) {
            long row = rowbase + m * 16 + rq + r;
            if (row < NN) {
#pragma unroll
                for (int nb = 0; nb < 8; nb++)
                    y1[row * 128 + nb * 16 + lr] = f2b(acc[m][nb][r]);
            }
        }
    }
}

// ---------------- GEMM2: y2 = bf16( h @ W2^T ), h bf16 [NN,128], W2 [64,128] ----------------

__global__ __launch_bounds__(256) void gemm2_k(const ushort* __restrict__ h,
                                               const float* __restrict__ W2,
                                               ushort* __restrict__ y2) {
    __shared__ ushort wl[64 * 136];
    int tid = threadIdx.x;
    for (int i = tid; i < 64 * 128; i += 256)
        wl[(i >> 7) * 136 + (i & 127)] = f2b(W2[i]);
    __syncthreads();

    int wave = tid >> 6, lane = tid & 63;
    int lr = lane & 15, lk = (lane >> 4) * 8;
    long rowbase = (long)blockIdx.x * 128 + wave * 32;

    f32x4 acc[2][4] = {};
    for (int kc = 0; kc < 128; kc += 32) {
        bf16x8 a[2];
#pragma unroll
        for (int m = 0; m < 2; m++) {
            long row = rowbase + m * 16 + lr;
            if (row > NN - 1) row = NN - 1;
            a[m] = *(const bf16x8*)(h + row * 128 + kc + lk);
        }
#pragma unroll
        for (int nb = 0; nb < 4; nb++) {
            bf16x8 b = *(const bf16x8*)&wl[(nb * 16 + lr) * 136 + kc + lk];
            acc[0][nb] = __builtin_amdgcn_mfma_f32_16x16x32_bf16(a[0], b, acc[0][nb], 0, 0, 0);
            acc[1][nb] = __builtin_amdgcn_mfma_f32_16x16x32_bf16(a[1], b, acc[1][nb], 0, 0, 0);
        }
    }
    int rq = (lane >> 4) * 4;
#pragma unroll
    for (int m = 0; m < 2; m++) {
#pragma unroll
        for (int r = 0; r < 4; r++) {
            long row = rowbase + m * 16 + rq + r;
            if (row < NN) {
#pragma unroll
                for (int nb = 0; nb < 4; nb++)
                    y2[row * 64 + nb * 16 + lr] = f2b(acc[m][nb][r]);
            }
        }
    }
}

// ---------------- Aggregation (pull over CSR), fused bias (+relu for layer1) ----------------
// One wave per node. Layer 1: D=128, lane covers 2 dims (one dword of 2 bf16).

__global__ __launch_bounds__(256) void agg1_k(const ushort* __restrict__ y1,
                                              const int* __restrict__ ptr,
                                              const int* __restrict__ col,
                                              const float* __restrict__ b1,
                                              ushort* __restrict__ h) {
    int wid = (blockIdx.x * 256 + threadIdx.x) >> 6;
    int lane = threadIdx.x & 63;
    if (wid >= NN) return;
    int s0 = ptr[wid], s1 = ptr[wid + 1];

    uint v = *(const uint*)(y1 + (size_t)wid * 128 + lane * 2);
    float a0 = bflo(v), a1 = bfhi(v);

    for (int i = s0; i < s1; i += 64) {
        int m = s1 - i;
        if (m > 64) m = 64;
        int sv = (lane < m) ? col[i + lane] : 0;
        for (int j = 0; j < m; j++) {
            int sj = __shfl(sv, j);
            uint u = *(const uint*)(y1 + (size_t)sj * 128 + lane * 2);
            a0 += bflo(u);
            a1 += bfhi(u);
        }
    }
    a0 = fmaxf(a0 + b1[2 * lane], 0.f);
    a1 = fmaxf(a1 + b1[2 * lane + 1], 0.f);
    uint o = (uint)f2b(a0) | ((uint)f2b(a1) << 16);
    *(uint*)(h + (size_t)wid * 128 + lane * 2) = o;
}

// Layer 2: D=64, lane covers 1 dim, fp32 output, no relu.
__global__ __launch_bounds__(256) void agg2_k(const ushort* __restrict__ y2,
                                              const int* __restrict__ ptr,
                                              const int* __restrict__ col,
                                              const float* __restrict__ b2,
                                              float* __restrict__ out) {
    int wid = (blockIdx.x * 256 + threadIdx.x) >> 6;
    int lane = threadIdx.x & 63;
    if (wid >= NN) return;
    int s0 = ptr[wid], s1 = ptr[wid + 1];

    float a = b2f(y2[(size_t)wid * 64 + lane]);

    for (int i = s0; i < s1; i += 64) {
        int m = s1 - i;
        if (m > 64) m = 64;
        int sv = (lane < m) ? col[i + lane] : 0;
        for (int j = 0; j < m; j++) {
            int sj = __shfl(sv, j);
            a += b2f(y2[(size_t)sj * 64 + lane]);
        }
    }
    out[(size_t)wid * 64 + lane] = a + b2[lane];
}

// ---------------- launch ----------------

static constexpr size_t alup(size_t x) { return (x + 255) & ~(size_t)255; }
static constexpr size_t OFF_PTR  = 0;
static constexpr size_t OFF_CUR  = alup(OFF_PTR + (NN + 1) * 4);
static constexpr size_t OFF_COL  = alup(OFF_CUR + NN * 4);
static constexpr size_t OFF_PART = alup(OFF_COL + (size_t)NE * 4);
static constexpr size_t OFF_Y1   = alup(OFF_PART + 256);
static constexpr size_t OFF_H    = alup(OFF_Y1 + (size_t)NN * 128 * 2);
static constexpr size_t OFF_Y2   = alup(OFF_H + (size_t)NN * 128 * 2);

extern "C" void kernel_launch(void* const* d_in, const int* in_sizes, int n_in,
                              void* d_out, int out_size, void* d_ws, size_t ws_size,
                              hipStream_t stream) {
    const float* x  = (const float*)d_in[0];
    const int*   ei = (const int*)d_in[1];
    const float* W1 = (const float*)d_in[2];
    const float* b1 = (const float*)d_in[3];
    const float* W2 = (const float*)d_in[4];
    const float* b2 = (const float*)d_in[5];
    float* out = (float*)d_out;
    char* ws = (char*)d_ws;

    int* ptr  = (int*)(ws + OFF_PTR);
    int* cur  = (int*)(ws + OFF_CUR);
    int* colA = (int*)(ws + OFF_COL);
    int* part = (int*)(ws + OFF_PART);
    ushort* y1 = (ushort*)(ws + OFF_Y1);
    ushort* hh = (ushort*)(ws + OFF_H);
    ushort* y2 = (ushort*)(ws + OFF_Y2);

    hipMemsetAsync(ptr, 0, (NN + 1) * sizeof(int), stream);
    hipLaunchKernelGGL(hist_k,  dim3(2048), dim3(256), 0, stream, ei, ptr);
    hipLaunchKernelGGL(scan1_k, dim3(25),   dim3(256), 0, stream, ptr, part, NN + 1);
    hipLaunchKernelGGL(scan2_k, dim3(1),    dim3(64),  0, stream, part, 25);
    hipLaunchKernelGGL(scan3_k, dim3(391),  dim3(256), 0, stream, ptr, part, cur, NN + 1);
    hipLaunchKernelGGL(fill_k,  dim3(2048), dim3(256), 0, stream, ei, cur, colA);

    hipLaunchKernelGGL(gemm1_k, dim3(782),  dim3(256), 0, stream, x, W1, y1);
    hipLaunchKernelGGL(agg1_k,  dim3(25000),dim3(256), 0, stream, y1, ptr, colA, b1, hh);
    hipLaunchKernelGGL(gemm2_k, dim3(782),  dim3(256), 0, stream, hh, W2, y2);
    hipLaunchKernelGGL(agg2_k,  dim3(25000),dim3(256), 0, stream, y2, ptr, colA, b2, out);
}